// Round 8
// baseline (374.547 us; speedup 1.0000x reference)
//
#include <hip/hip_runtime.h>
#include <hip/hip_bf16.h>

// Problem constants (fixed by setup_inputs):
//   bs=8, nq=1500, C=2  -> NI = 12000 rows
//   total_tgt = 4800    -> NJ = 4800 cols
// Output: [NI][NJ] f32 = 230.4 MB  -> write-BW bound (~35 us @6.6 TB/s).
// In-window harness poison-fill (921.6 MB, ~140 us) sets the total floor.
//
// C[i,j] = softplus(x0)+softplus(x1) - t0*x0 - t1*x1 + 5*(|px-tx|+|py-ty|)
//
// R8 PROBE: single fused kernel (no precompute, no d_ws), launched TWICE.
// dur_R8 - 227 ~= one cmat pass. Disambiguates cmat=40us (roofline+overhead
// model) vs cmat=82us (slow-store model). Writes are idempotent.

#define NI 12000
#define NJ 4800
#define NJF (NJ / 4)      // 1200 float4-columns per row
#define ROWS 4            // rows per inner group
#define RITER 5           // row-groups per block -> 20 rows/block

typedef float f32x4 __attribute__((ext_vector_type(4)));

__device__ __forceinline__ float softplus(float x) {
    // stable: max(x,0) + log1p(exp(-|x|))
    return fmaxf(x, 0.0f) + log1pf(expf(-fabsf(x)));
}

__device__ __forceinline__ float cost_elem(f32x4 q, float pyr, f32x4 t) {
    float cc = q.x + q.y * t.x + q.z * t.y;
    float cp = fabsf(q.w - t.z) + fabsf(pyr - t.w);
    return fmaf(5.0f, cp, cc);
}

// Fused: each thread owns 4 output cols (targets in registers), loops over
// 20 rows computing row params (softplus etc.) inline. No workspace.
// grid (5, 600) = 3000 blocks (~12/CU), 256 thr.
__global__ __launch_bounds__(256) void fused_cmat_kernel(
    const float* __restrict__ pred_logits,   // [NI][2]
    const float* __restrict__ pred_points,   // [NI][2]
    const float* __restrict__ tgt_labels,    // [NJ][2]
    const float* __restrict__ tgt_points,    // [NJ][2]
    f32x4* __restrict__ out)                 // [NI][NJF]
{
    int jf = blockIdx.x * blockDim.x + threadIdx.x;   // float4-column index
    if (jf >= NJF) return;

    const float2* lab = (const float2*)tgt_labels;
    const float2* tpt = (const float2*)tgt_points;
    const float2* plg = (const float2*)pred_logits;
    const float2* ppt = (const float2*)pred_points;

    // 4 targets for this thread's 4 output columns, loaded once (L1/L2-hot)
    f32x4 t0, t1, t2, t3;
    {
        float2 l, p;
        l = lab[jf * 4 + 0]; p = tpt[jf * 4 + 0]; t0 = (f32x4){l.x, l.y, p.x, p.y};
        l = lab[jf * 4 + 1]; p = tpt[jf * 4 + 1]; t1 = (f32x4){l.x, l.y, p.x, p.y};
        l = lab[jf * 4 + 2]; p = tpt[jf * 4 + 2]; t2 = (f32x4){l.x, l.y, p.x, p.y};
        l = lab[jf * 4 + 3]; p = tpt[jf * 4 + 3]; t3 = (f32x4){l.x, l.y, p.x, p.y};
    }

    int i00 = blockIdx.y * (ROWS * RITER);
#pragma unroll
    for (int g = 0; g < RITER; ++g) {
#pragma unroll
        for (int r = 0; r < ROWS; ++r) {
            int i = i00 + g * ROWS + r;
            float2 lg = plg[i];          // wave-uniform -> scalar path
            float2 pp = ppt[i];
            f32x4 q;
            q.x = softplus(lg.x) + softplus(lg.y);
            q.y = -lg.x;
            q.z = -lg.y;
            q.w = pp.x;
            float pyr = pp.y;
            f32x4 o;
            o.x = cost_elem(q, pyr, t0);
            o.y = cost_elem(q, pyr, t1);
            o.z = cost_elem(q, pyr, t2);
            o.w = cost_elem(q, pyr, t3);
            out[i * NJF + jf] = o;
        }
    }
}

extern "C" void kernel_launch(void* const* d_in, const int* in_sizes, int n_in,
                              void* d_out, int out_size, void* d_ws, size_t ws_size,
                              hipStream_t stream) {
    const float* pred_logits = (const float*)d_in[0];  // 24000
    const float* pred_points = (const float*)d_in[1];  // 24000
    const float* tgt_labels  = (const float*)d_in[2];  // 9600
    const float* tgt_points  = (const float*)d_in[3];  // 9600
    float* out = (float*)d_out;                        // 57,600,000

    dim3 block(256);
    dim3 grid((NJF + 255) / 256, NI / (ROWS * RITER));   // (5, 600)

    // PROBE: launch twice (idempotent). dur - 227 ~= one pass duration.
    fused_cmat_kernel<<<grid, block, 0, stream>>>(
        pred_logits, pred_points, tgt_labels, tgt_points, (f32x4*)out);
    fused_cmat_kernel<<<grid, block, 0, stream>>>(
        pred_logits, pred_points, tgt_labels, tgt_points, (f32x4*)out);
}

// Round 10
// 225.076 us; speedup vs baseline: 1.6641x; 1.6641x over previous
//
#include <hip/hip_runtime.h>
#include <hip/hip_bf16.h>

// Problem constants (fixed by setup_inputs):
//   bs=8, nq=1500, C=2  -> NI = 12000 rows
//   total_tgt = 4800    -> NJ = 4800 cols
// Output: [NI][NJ] f32 = 230.4 MB  -> write roofline ~35 us @6.6 TB/s.
//
// C[i,j] = softplus(x0)+softplus(x1) - t0*x0 - t1*x1 + 5*(|px-tx|+|py-ty|)
// (log_sigmoid(x) - log_sigmoid(-x) = x; mean-over-2 /2 cancels COST_CLASS=2)
//
// R8 findings (rocprof, fused probe): cmat was 152.9us @1.5TB/s, VALUBusy 55%
// -> transcendental row-params recomputed by all 256 threads/block.
// R9: single fused kernel, row-params computed ONCE per block into LDS
// (threads 0..19), broadcast-read in the store loop.

#define NI 12000
#define NJ 4800
#define NJF (NJ / 4)      // 1200 float4-columns per row
#define ROWSPB 20         // rows per block

typedef float f32x4 __attribute__((ext_vector_type(4)));

__device__ __forceinline__ float softplus(float x) {
    // stable: max(x,0) + log1p(exp(-|x|)) — only 20 threads/block run this
    return fmaxf(x, 0.0f) + log1pf(expf(-fabsf(x)));
}

__device__ __forceinline__ float cost_elem(f32x4 q, float pyr, f32x4 t) {
    float cc = q.x + q.y * t.x + q.z * t.y;
    float cp = fabsf(q.w - t.z) + fabsf(pyr - t.w);
    return fmaf(5.0f, cp, cc);
}

// grid (5, 600), 256 thr. Each thread: 4 output cols (targets in regs),
// 20 rows -> 20 coalesced 16B stores. Row params from LDS broadcast.
__global__ __launch_bounds__(256) void fused_cmat_kernel(
    const float* __restrict__ pred_logits,   // [NI][2]
    const float* __restrict__ pred_points,   // [NI][2]
    const float* __restrict__ tgt_labels,    // [NJ][2]
    const float* __restrict__ tgt_points,    // [NJ][2]
    f32x4* __restrict__ out)                 // [NI][NJF]
{
    __shared__ f32x4 s_q[ROWSPB];    // (base, -x0, -x1, px) per row
    __shared__ float s_py[ROWSPB];   // py per row

    const float2* plg = (const float2*)pred_logits;
    const float2* ppt = (const float2*)pred_points;
    const float2* lab = (const float2*)tgt_labels;
    const float2* tpt = (const float2*)tgt_points;

    // cooperative row-param precompute: one row per thread, 20 threads
    if (threadIdx.x < ROWSPB) {
        int i = blockIdx.y * ROWSPB + threadIdx.x;
        float2 lg = plg[i];
        float2 pp = ppt[i];
        f32x4 q;
        q.x = softplus(lg.x) + softplus(lg.y);  // base
        q.y = -lg.x;                            // coeff for t0
        q.z = -lg.y;                            // coeff for t1
        q.w = pp.x;                             // px
        s_q[threadIdx.x]  = q;
        s_py[threadIdx.x] = pp.y;
    }

    int jf = blockIdx.x * blockDim.x + threadIdx.x;   // float4-column index

    // 4 targets for this thread's 4 output columns, loaded once (L1/L2-hot)
    f32x4 t0, t1, t2, t3;
    if (jf < NJF) {
        float2 l, p;
        l = lab[jf * 4 + 0]; p = tpt[jf * 4 + 0]; t0 = (f32x4){l.x, l.y, p.x, p.y};
        l = lab[jf * 4 + 1]; p = tpt[jf * 4 + 1]; t1 = (f32x4){l.x, l.y, p.x, p.y};
        l = lab[jf * 4 + 2]; p = tpt[jf * 4 + 2]; t2 = (f32x4){l.x, l.y, p.x, p.y};
        l = lab[jf * 4 + 3]; p = tpt[jf * 4 + 3]; t3 = (f32x4){l.x, l.y, p.x, p.y};
    }

    __syncthreads();                 // all threads reach this (return is below)
    if (jf >= NJF) return;

    int ibase = blockIdx.y * ROWSPB;
#pragma unroll
    for (int r = 0; r < ROWSPB; ++r) {
        f32x4 q   = s_q[r];          // same-address LDS read -> broadcast
        float pyr = s_py[r];
        f32x4 o;
        o.x = cost_elem(q, pyr, t0);
        o.y = cost_elem(q, pyr, t1);
        o.z = cost_elem(q, pyr, t2);
        o.w = cost_elem(q, pyr, t3);
        out[(ibase + r) * NJF + jf] = o;   // coalesced 16B/lane
    }
}

extern "C" void kernel_launch(void* const* d_in, const int* in_sizes, int n_in,
                              void* d_out, int out_size, void* d_ws, size_t ws_size,
                              hipStream_t stream) {
    const float* pred_logits = (const float*)d_in[0];  // 24000
    const float* pred_points = (const float*)d_in[1];  // 24000
    const float* tgt_labels  = (const float*)d_in[2];  // 9600
    const float* tgt_points  = (const float*)d_in[3];  // 9600
    float* out = (float*)d_out;                        // 57,600,000

    dim3 block(256);
    dim3 grid((NJF + 255) / 256, NI / ROWSPB);   // (5, 600)
    fused_cmat_kernel<<<grid, block, 0, stream>>>(
        pred_logits, pred_points, tgt_labels, tgt_points, (f32x4*)out);
}